// Round 3
// baseline (352.597 us; speedup 1.0000x reference)
//
#include <hip/hip_runtime.h>

// RBF causal attention: out[m] = sum_{j<=m} exp(-0.125*||q_m - k_j||^2) * v_j
// B=2 H=16 S=2048 D=64, fp32 in/out.
// fp16 hi/lo-split QK (3 MFMAs ~ fp32 accuracy), fp16 PV with p scaled 2^14.
// R3: Q fragments global->register (no Q LDS => 33KB LDS => 4 blocks/CU),
// grid 1024 (4 arcs per qt-pair), always-atomic flush, prefetch after QK,
// ksq bias fold.

constexpr int S_LEN = 2048;
constexpr int HD    = 64;
constexpr int BM    = 128;   // Q rows per block tile (4 waves x 2 strips x 16)
constexpr int BN    = 64;    // K/V rows per tile
constexpr float SCALE = 0.125f;
constexpr float LOG2E = 1.44269504088896f;

typedef _Float16 half8 __attribute__((ext_vector_type(8)));
typedef _Float16 half4 __attribute__((ext_vector_type(4)));
typedef float    f32x4 __attribute__((ext_vector_type(4)));

// 16B-chunk XOR swizzle (rows of 64 halves = 8 chunks of 8).
__device__ __forceinline__ int swz(int row, int chunk) {
  return (row << 3) + (chunk ^ (row & 7));
}

__global__ __launch_bounds__(256, 4)
void rbf_causal_attn(const float* __restrict__ Qp, const float* __restrict__ Kp,
                     const float* __restrict__ Vp, float* __restrict__ Op) {
  __shared__ half8 sKh[BN * 8];      //  8 KB
  __shared__ half8 sKl[BN * 8];      //  8 KB
  __shared__ half8 sVt[HD * 8];      //  8 KB  v^T: row=d, col=j
  __shared__ half8 sP[4 * 16 * 8];   //  8 KB  per-wave P round-trip
  __shared__ float sQsq[BM];         // s*log2e*|q|^2
  __shared__ float sKsq[BN];         // s*log2e*|k|^2 - 14  (bias folded)

  const int x    = blockIdx.x;
  const int bh   = (x & 7) * 4 + ((x >> 3) & 3);  // 4 bh per XCD for K/V L2 reuse
  const int p    = (x >> 5) & 7;     // pair index
  const int a    = (x >> 8) & 3;     // arc 0..3
  const int qtA  = 15 - p;           // 8..15
  const int nA   = 2 * qtA + 2;      // 18..32 j-tiles for tile A
  const int qtB  = p;
  const int g0   = (a < 2) ? 9 * a       : 18 + 8 * (a - 2);   // {0,9,18,26}
  const int g1   = (a < 2) ? 9 * (a + 1) : 26 + 8 * (a - 2);   // {9,18,26,34}

  const int t    = threadIdx.x;
  const int w    = t >> 6;
  const int lane = t & 63;
  const int ln   = lane & 15;
  const int q4   = lane >> 4;

  const float* Kg = Kp + (size_t)bh * S_LEN * HD;
  const float* Vg = Vp + (size_t)bh * S_LEN * HD;

  f32x4 kreg[4];      // K prefetch registers (one tile)
  float vreg[16];     // V prefetch registers (one tile, column d=lane)
  half8 qh[2][2], ql[2][2];
  f32x4 oacc[2][4] = {};   // scaled by 2^14

  // ---- load this wave's Q fragments straight from global; row |q|^2 ----
  auto load_q = [&](int qt) {
    const float* Qg = Qp + ((size_t)bh * S_LEN + (size_t)qt * BM) * HD;
    #pragma unroll
    for (int s = 0; s < 2; ++s) {
      float ss = 0.f;
      #pragma unroll
      for (int kc = 0; kc < 2; ++kc) {
        const float* base = Qg + (w * 32 + s * 16 + ln) * HD + kc * 32 + q4 * 8;
        const f32x4 fa = *(const f32x4*)base;
        const f32x4 fb = *(const f32x4*)(base + 4);
        half8 h, l;
        #pragma unroll
        for (int c = 0; c < 4; ++c) {
          const float va = fa[c], vb = fb[c];
          const _Float16 ha = (_Float16)va, hb = (_Float16)vb;
          h[c]     = ha;  h[c + 4] = hb;
          l[c]     = (_Float16)(va - (float)ha);
          l[c + 4] = (_Float16)(vb - (float)hb);
          ss += va * va + vb * vb;
        }
        qh[s][kc] = h;  ql[s][kc] = l;
      }
      ss += __shfl_xor(ss, 16);
      ss += __shfl_xor(ss, 32);
      if (q4 == 0) sQsq[w * 32 + s * 16 + ln] = ss * (SCALE * LOG2E);
    }
  };

  // ---- issue global loads for j-tile jt into registers (no wait) ----
  auto prefetch = [&](int jt) {
    const float* Kt = Kg + (size_t)jt * BN * HD;
    #pragma unroll
    for (int i = 0; i < 4; ++i) {
      const int id = t + 256 * i;
      kreg[i] = *(const f32x4*)(Kt + (id >> 4) * HD + (id & 15) * 4);
    }
    const float* Vt = Vg + (size_t)jt * BN * HD;
    #pragma unroll
    for (int i = 0; i < 16; ++i)
      vreg[i] = Vt[(w * 16 + i) * HD + lane];   // 256B-coalesced per instr
  };

  // ---- convert prefetched K/V registers into LDS ----
  auto stage_kv = [&]() {
    #pragma unroll
    for (int i = 0; i < 4; ++i) {
      const int id  = t + 256 * i;
      const int row = id >> 4;
      const int d4  = id & 15;
      const f32x4 f = kreg[i];
      half4 hv, lv;
      float ss = 0.f;
      #pragma unroll
      for (int c = 0; c < 4; ++c) {
        const float fv = f[c];
        const _Float16 hi = (_Float16)fv;
        hv[c] = hi;
        lv[c] = (_Float16)(fv - (float)hi);
        ss += fv * fv;
      }
      ((half4*)&sKh[swz(row, d4 >> 1)])[d4 & 1] = hv;
      ((half4*)&sKl[swz(row, d4 >> 1)])[d4 & 1] = lv;
      #pragma unroll
      for (int m = 1; m < 16; m <<= 1) ss += __shfl_xor(ss, m);
      if ((t & 15) == 0) sKsq[row] = ss * (SCALE * LOG2E) - 14.0f;
    }
    // V: thread holds column d=lane, rows j = w*16..w*16+15 -> transposed store
    half8 v0, v1;
    #pragma unroll
    for (int i = 0; i < 8; ++i) { v0[i] = (_Float16)vreg[i]; v1[i] = (_Float16)vreg[8 + i]; }
    sVt[swz(lane, 2 * w + 0)] = v0;
    sVt[swz(lane, 2 * w + 1)] = v1;
  };

  // ---- one j-tile: QK (hi/lo), prefetch njt, exp2, P round-trip, PV ----
  auto compute = [&](int qt, int jt, int njt) {
    f32x4 acc[2][4] = {};
    #pragma unroll
    for (int kc = 0; kc < 2; ++kc)
      #pragma unroll
      for (int nt = 0; nt < 4; ++nt) {
        const int row = nt * 16 + ln;
        const int ch  = ((kc << 2) + q4) ^ (ln & 7);
        const half8 kh = sKh[(row << 3) + ch];
        const half8 kl = sKl[(row << 3) + ch];
        acc[0][nt] = __builtin_amdgcn_mfma_f32_16x16x32_f16(qh[0][kc], kh, acc[0][nt], 0, 0, 0);
        acc[0][nt] = __builtin_amdgcn_mfma_f32_16x16x32_f16(qh[0][kc], kl, acc[0][nt], 0, 0, 0);
        acc[0][nt] = __builtin_amdgcn_mfma_f32_16x16x32_f16(ql[0][kc], kh, acc[0][nt], 0, 0, 0);
        acc[1][nt] = __builtin_amdgcn_mfma_f32_16x16x32_f16(qh[1][kc], kh, acc[1][nt], 0, 0, 0);
        acc[1][nt] = __builtin_amdgcn_mfma_f32_16x16x32_f16(qh[1][kc], kl, acc[1][nt], 0, 0, 0);
        acc[1][nt] = __builtin_amdgcn_mfma_f32_16x16x32_f16(ql[1][kc], kh, acc[1][nt], 0, 0, 0);
      }

    if (njt >= 0) prefetch(njt);   // kreg/vreg dead during QK; refill here

    const bool need_mask = (jt >= 2 * qt);
    half8 pa[2][2];
    #pragma unroll
    for (int s = 0; s < 2; ++s) {
      const int m0 = w * 32 + s * 16;
      float qsqv[4];
      #pragma unroll
      for (int r = 0; r < 4; ++r) qsqv[r] = sQsq[m0 + q4 * 4 + r];
      #pragma unroll
      for (int nt = 0; nt < 4; ++nt) {
        const float ks = sKsq[nt * 16 + ln];
        #pragma unroll
        for (int r = 0; r < 4; ++r) {
          // log2(2^14 p) = 2s*log2e*qk - s*log2e*q^2 - (s*log2e*k^2 - 14)
          const float lg = __builtin_fmaf((2.f * SCALE * LOG2E), acc[s][nt][r], -qsqv[r]) - ks;
          float pv = exp2f(lg);
          if (need_mask) {
            const int jg = jt * BN + nt * 16 + ln;
            const int mg = qt * BM + m0 + q4 * 4 + r;
            if (jg > mg) pv = 0.f;
          }
          const int prow = q4 * 4 + r;       // C-layout: row = quad*4+reg
          const int col  = nt * 16 + ln;     //           col = lane&15
          ((_Float16*)&sP[(w << 7) + swz(prow, col >> 3)])[col & 7] = (_Float16)pv;
        }
      }
      // A-operand re-read (per-wave buffer; compiler orders vs next overwrite)
      #pragma unroll
      for (int kc = 0; kc < 2; ++kc)
        pa[s][kc] = sP[(w << 7) + swz(ln, (kc << 2) + q4)];
    }

    #pragma unroll
    for (int dt = 0; dt < 4; ++dt) {
      const int row = dt * 16 + ln;
      const half8 vf0 = sVt[(row << 3) + ((0 + q4) ^ (ln & 7))];
      const half8 vf1 = sVt[(row << 3) + ((4 + q4) ^ (ln & 7))];
      #pragma unroll
      for (int s = 0; s < 2; ++s) {
        oacc[s][dt] = __builtin_amdgcn_mfma_f32_16x16x32_f16(pa[s][0], vf0, oacc[s][dt], 0, 0, 0);
        oacc[s][dt] = __builtin_amdgcn_mfma_f32_16x16x32_f16(pa[s][1], vf1, oacc[s][dt], 0, 0, 0);
      }
    }
  };

  // ---- flush accumulator (x 2^-14), atomic (tiles have multiple owners) ----
  auto flush = [&](int qt) {
    #pragma unroll
    for (int s = 0; s < 2; ++s)
      #pragma unroll
      for (int dt = 0; dt < 4; ++dt)
        #pragma unroll
        for (int r = 0; r < 4; ++r) {
          const int row = qt * BM + w * 32 + s * 16 + q4 * 4 + r;
          atomicAdd(Op + ((size_t)bh * S_LEN + row) * HD + dt * 16 + ln,
                    oacc[s][dt][r] * 6.103515625e-05f);
        }
  };

  // ---- main: arc [g0, g1) of the pair's 34 j-tile iterations ----
  int qt, jt;
  if (g0 < nA) { qt = qtA; jt = g0; }
  else         { qt = qtB; jt = g0 - nA; }
  load_q(qt);
  prefetch(jt);
  __syncthreads();

  const int niter = g1 - g0;
  #pragma unroll 1
  for (int step = 0; step < niter; ++step) {
    if (qt == qtA && jt == nA) {       // cross from tile A into tile B
      flush(qtA);
      #pragma unroll
      for (int s = 0; s < 2; ++s)
        #pragma unroll
        for (int dt = 0; dt < 4; ++dt) oacc[s][dt] = f32x4{0.f, 0.f, 0.f, 0.f};
      load_q(qtB);
      qt = qtB; jt = 0;
    }
    stage_kv();
    __syncthreads();
    int njt = -1;
    if (step + 1 < niter) {
      njt = jt + 1;
      if (qt == qtA && njt == nA) njt = 0;
    }
    compute(qt, jt, njt);
    __syncthreads();
    ++jt;
  }
  flush(qt);
}

extern "C" void kernel_launch(void* const* d_in, const int* in_sizes, int n_in,
                              void* d_out, int out_size, void* d_ws, size_t ws_size,
                              hipStream_t stream) {
  const float* q = (const float*)d_in[0];
  const float* k = (const float*)d_in[1];
  const float* v = (const float*)d_in[2];
  float* o = (float*)d_out;
  hipMemsetAsync(d_out, 0, (size_t)out_size * sizeof(float), stream);
  rbf_causal_attn<<<dim3(1024), dim3(256), 0, stream>>>(q, k, v, o);
}

// Round 4
// 303.374 us; speedup vs baseline: 1.1623x; 1.1623x over previous
//
#include <hip/hip_runtime.h>

// RBF causal attention: out[m] = sum_{j<=m} exp(-0.125*||q_m - k_j||^2) * v_j
// B=2 H=16 S=2048 D=64, fp32 in/out.
// fp16 hi/lo-split QK (3 MFMAs ~ fp32 accuracy), fp16 PV with p scaled 2^14.
// R4: launch_bounds(256,3) (170-reg cap -- (256,4)'s 128 cap caused massive
// scratch spill, FETCH 463MB), grid 768 = 3 blocks/CU exactly (arcs 12/11/11),
// qsq in registers (shuffle broadcast once per q-tile, no LDS reads per iter).

constexpr int S_LEN = 2048;
constexpr int HD    = 64;
constexpr int BM    = 128;   // Q rows per block tile (4 waves x 2 strips x 16)
constexpr int BN    = 64;    // K/V rows per tile
constexpr float SCALE = 0.125f;
constexpr float LOG2E = 1.44269504088896f;

typedef _Float16 half8 __attribute__((ext_vector_type(8)));
typedef _Float16 half4 __attribute__((ext_vector_type(4)));
typedef float    f32x4 __attribute__((ext_vector_type(4)));

// 16B-chunk XOR swizzle (rows of 64 halves = 8 chunks of 8).
__device__ __forceinline__ int swz(int row, int chunk) {
  return (row << 3) + (chunk ^ (row & 7));
}

__global__ __launch_bounds__(256, 3)
void rbf_causal_attn(const float* __restrict__ Qp, const float* __restrict__ Kp,
                     const float* __restrict__ Vp, float* __restrict__ Op) {
  __shared__ half8 sKh[BN * 8];      //  8 KB
  __shared__ half8 sKl[BN * 8];      //  8 KB
  __shared__ half8 sVt[HD * 8];      //  8 KB  v^T: row=d, col=j
  __shared__ half8 sP[4 * 16 * 8];   //  8 KB  per-wave P round-trip
  __shared__ float sKsq[BN];         // s*log2e*|k|^2 - 14  (bias folded)

  const int x    = blockIdx.x;
  const int bh   = (x & 7) * 4 + ((x >> 3) & 3);  // 4 bh per XCD for K/V L2 reuse
  const int p    = (x >> 5) & 7;     // pair index
  const int a    = x >> 8;           // arc 0..2
  const int qtA  = 15 - p;           // 8..15
  const int nA   = 2 * qtA + 2;      // 18..32 j-tiles for tile A
  const int qtB  = p;
  const int g0   = (a == 0) ? 0 : (a == 1 ? 12 : 23);
  const int g1   = (a == 0) ? 12 : (a == 1 ? 23 : 34);

  const int t    = threadIdx.x;
  const int w    = t >> 6;
  const int lane = t & 63;
  const int ln   = lane & 15;
  const int q4   = lane >> 4;

  const float* Kg = Kp + (size_t)bh * S_LEN * HD;
  const float* Vg = Vp + (size_t)bh * S_LEN * HD;

  f32x4 kreg[4];      // K prefetch registers (one tile)
  float vreg[16];     // V prefetch registers (one tile, column d=lane)
  half8 qh[2][2], ql[2][2];
  float qsqv[2][4];   // s*log2e*|q_row|^2 for rows q4*4+r of each strip
  f32x4 oacc[2][4] = {};   // scaled by 2^14

  // ---- load this wave's Q fragments straight from global; row |q|^2 ----
  auto load_q = [&](int qt) {
    const float* Qg = Qp + ((size_t)bh * S_LEN + (size_t)qt * BM) * HD;
    #pragma unroll
    for (int s = 0; s < 2; ++s) {
      float ss = 0.f;
      #pragma unroll
      for (int kc = 0; kc < 2; ++kc) {
        const float* base = Qg + (w * 32 + s * 16 + ln) * HD + kc * 32 + q4 * 8;
        const f32x4 fa = *(const f32x4*)base;
        const f32x4 fb = *(const f32x4*)(base + 4);
        half8 h, l;
        #pragma unroll
        for (int c = 0; c < 4; ++c) {
          const float va = fa[c], vb = fb[c];
          const _Float16 ha = (_Float16)va, hb = (_Float16)vb;
          h[c]     = ha;  h[c + 4] = hb;
          l[c]     = (_Float16)(va - (float)ha);
          l[c + 4] = (_Float16)(vb - (float)hb);
          ss += va * va + vb * vb;
        }
        qh[s][kc] = h;  ql[s][kc] = l;
      }
      ss += __shfl_xor(ss, 16);      // sum over q4 groups -> row sum at lane ln
      ss += __shfl_xor(ss, 32);
      ss *= (SCALE * LOG2E);
      // broadcast: lane needs rows q4*4+r (held at lanes with ln = q4*4+r)
      #pragma unroll
      for (int r = 0; r < 4; ++r) qsqv[s][r] = __shfl(ss, q4 * 4 + r);
    }
  };

  // ---- issue global loads for j-tile jt into registers (no wait) ----
  auto prefetch = [&](int jt) {
    const float* Kt = Kg + (size_t)jt * BN * HD;
    #pragma unroll
    for (int i = 0; i < 4; ++i) {
      const int id = t + 256 * i;
      kreg[i] = *(const f32x4*)(Kt + (id >> 4) * HD + (id & 15) * 4);
    }
    const float* Vt = Vg + (size_t)jt * BN * HD;
    #pragma unroll
    for (int i = 0; i < 16; ++i)
      vreg[i] = Vt[(w * 16 + i) * HD + lane];   // 256B-coalesced per instr
  };

  // ---- convert prefetched K/V registers into LDS ----
  auto stage_kv = [&]() {
    #pragma unroll
    for (int i = 0; i < 4; ++i) {
      const int id  = t + 256 * i;
      const int row = id >> 4;
      const int d4  = id & 15;
      const f32x4 f = kreg[i];
      half4 hv, lv;
      float ss = 0.f;
      #pragma unroll
      for (int c = 0; c < 4; ++c) {
        const float fv = f[c];
        const _Float16 hi = (_Float16)fv;
        hv[c] = hi;
        lv[c] = (_Float16)(fv - (float)hi);
        ss += fv * fv;
      }
      ((half4*)&sKh[swz(row, d4 >> 1)])[d4 & 1] = hv;
      ((half4*)&sKl[swz(row, d4 >> 1)])[d4 & 1] = lv;
      #pragma unroll
      for (int m = 1; m < 16; m <<= 1) ss += __shfl_xor(ss, m);
      if ((t & 15) == 0) sKsq[row] = ss * (SCALE * LOG2E) - 14.0f;
    }
    // V: thread holds column d=lane, rows j = w*16..w*16+15 -> transposed store
    half8 v0, v1;
    #pragma unroll
    for (int i = 0; i < 8; ++i) { v0[i] = (_Float16)vreg[i]; v1[i] = (_Float16)vreg[8 + i]; }
    sVt[swz(lane, 2 * w + 0)] = v0;
    sVt[swz(lane, 2 * w + 1)] = v1;
  };

  // ---- one j-tile: QK (hi/lo), prefetch njt, exp2, P round-trip, PV ----
  auto compute = [&](int qt, int jt, int njt) {
    f32x4 acc[2][4] = {};
    #pragma unroll
    for (int kc = 0; kc < 2; ++kc)
      #pragma unroll
      for (int nt = 0; nt < 4; ++nt) {
        const int row = nt * 16 + ln;
        const int ch  = ((kc << 2) + q4) ^ (ln & 7);
        const half8 kh = sKh[(row << 3) + ch];
        const half8 kl = sKl[(row << 3) + ch];
        acc[0][nt] = __builtin_amdgcn_mfma_f32_16x16x32_f16(qh[0][kc], kh, acc[0][nt], 0, 0, 0);
        acc[0][nt] = __builtin_amdgcn_mfma_f32_16x16x32_f16(qh[0][kc], kl, acc[0][nt], 0, 0, 0);
        acc[0][nt] = __builtin_amdgcn_mfma_f32_16x16x32_f16(ql[0][kc], kh, acc[0][nt], 0, 0, 0);
        acc[1][nt] = __builtin_amdgcn_mfma_f32_16x16x32_f16(qh[1][kc], kh, acc[1][nt], 0, 0, 0);
        acc[1][nt] = __builtin_amdgcn_mfma_f32_16x16x32_f16(qh[1][kc], kl, acc[1][nt], 0, 0, 0);
        acc[1][nt] = __builtin_amdgcn_mfma_f32_16x16x32_f16(ql[1][kc], kh, acc[1][nt], 0, 0, 0);
      }

    if (njt >= 0) prefetch(njt);   // kreg/vreg dead during QK; refill here

    const bool need_mask = (jt >= 2 * qt);
    half8 pa[2][2];
    #pragma unroll
    for (int s = 0; s < 2; ++s) {
      const int m0 = w * 32 + s * 16;
      #pragma unroll
      for (int nt = 0; nt < 4; ++nt) {
        const float ks = sKsq[nt * 16 + ln];
        #pragma unroll
        for (int r = 0; r < 4; ++r) {
          // log2(2^14 p) = 2s*log2e*qk - s*log2e*q^2 - (s*log2e*k^2 - 14)
          const float lg = __builtin_fmaf((2.f * SCALE * LOG2E), acc[s][nt][r], -qsqv[s][r]) - ks;
          float pv = __builtin_amdgcn_exp2f(lg);
          if (need_mask) {
            const int jg = jt * BN + nt * 16 + ln;
            const int mg = qt * BM + m0 + q4 * 4 + r;
            if (jg > mg) pv = 0.f;
          }
          const int prow = q4 * 4 + r;       // C-layout: row = quad*4+reg
          const int col  = nt * 16 + ln;     //           col = lane&15
          ((_Float16*)&sP[(w << 7) + swz(prow, col >> 3)])[col & 7] = (_Float16)pv;
        }
      }
      // A-operand re-read (per-wave buffer)
      #pragma unroll
      for (int kc = 0; kc < 2; ++kc)
        pa[s][kc] = sP[(w << 7) + swz(ln, (kc << 2) + q4)];
    }

    #pragma unroll
    for (int dt = 0; dt < 4; ++dt) {
      const int row = dt * 16 + ln;
      const half8 vf0 = sVt[(row << 3) + ((0 + q4) ^ (ln & 7))];
      const half8 vf1 = sVt[(row << 3) + ((4 + q4) ^ (ln & 7))];
      #pragma unroll
      for (int s = 0; s < 2; ++s) {
        oacc[s][dt] = __builtin_amdgcn_mfma_f32_16x16x32_f16(pa[s][0], vf0, oacc[s][dt], 0, 0, 0);
        oacc[s][dt] = __builtin_amdgcn_mfma_f32_16x16x32_f16(pa[s][1], vf1, oacc[s][dt], 0, 0, 0);
      }
    }
  };

  // ---- flush accumulator (x 2^-14), atomic (tiles have multiple owners) ----
  auto flush = [&](int qt) {
    #pragma unroll
    for (int s = 0; s < 2; ++s)
      #pragma unroll
      for (int dt = 0; dt < 4; ++dt)
        #pragma unroll
        for (int r = 0; r < 4; ++r) {
          const int row = qt * BM + w * 32 + s * 16 + q4 * 4 + r;
          atomicAdd(Op + ((size_t)bh * S_LEN + row) * HD + dt * 16 + ln,
                    oacc[s][dt][r] * 6.103515625e-05f);
        }
  };

  // ---- main: arc [g0, g1) of the pair's 34 j-tile iterations ----
  int qt, jt;
  if (g0 < nA) { qt = qtA; jt = g0; }
  else         { qt = qtB; jt = g0 - nA; }
  load_q(qt);
  prefetch(jt);
  __syncthreads();

  const int niter = g1 - g0;
  #pragma unroll 1
  for (int step = 0; step < niter; ++step) {
    if (qt == qtA && jt == nA) {       // cross from tile A into tile B
      flush(qtA);
      #pragma unroll
      for (int s = 0; s < 2; ++s)
        #pragma unroll
        for (int dt = 0; dt < 4; ++dt) oacc[s][dt] = f32x4{0.f, 0.f, 0.f, 0.f};
      load_q(qtB);
      qt = qtB; jt = 0;
    }
    stage_kv();
    __syncthreads();
    int njt = -1;
    if (step + 1 < niter) {
      njt = jt + 1;
      if (qt == qtA && njt == nA) njt = 0;
    }
    compute(qt, jt, njt);
    __syncthreads();
    ++jt;
  }
  flush(qt);
}

extern "C" void kernel_launch(void* const* d_in, const int* in_sizes, int n_in,
                              void* d_out, int out_size, void* d_ws, size_t ws_size,
                              hipStream_t stream) {
  const float* q = (const float*)d_in[0];
  const float* k = (const float*)d_in[1];
  const float* v = (const float*)d_in[2];
  float* o = (float*)d_out;
  hipMemsetAsync(d_out, 0, (size_t)out_size * sizeof(float), stream);
  rbf_causal_attn<<<dim3(768), dim3(256), 0, stream>>>(q, k, v, o);
}

// Round 5
// 251.221 us; speedup vs baseline: 1.4035x; 1.2076x over previous
//
#include <hip/hip_runtime.h>

// RBF causal attention: out[m] = sum_{j<=m} exp(-0.125*||q_m - k_j||^2) * v_j
// B=2 H=16 S=2048 D=64, fp32 in/out.
// fp16 hi/lo-split QK (3 MFMAs ~ fp32 accuracy), fp16 PV with p scaled 2^14.
// R5: 1 strip/wave (BM=64) cuts arch-VGPR demand to ~90 (+32 acc) so 4
// waves/SIMD fits WITHOUT spill (R3/R4: unified file => arch+acc <= 512/waves;
// forcing launch_bounds above demand => scratch spill, FETCH 171-463MB).
// Grid 1024 = 4 blocks/CU exactly; pair (31-p, p) = 33 j-tiles in 2 arcs.

constexpr int S_LEN = 2048;
constexpr int HD    = 64;
constexpr int BM    = 64;    // Q rows per block (4 waves x 16 rows)
constexpr int BN    = 64;    // K/V rows per tile
constexpr float SCALE = 0.125f;
constexpr float LOG2E = 1.44269504088896f;

typedef _Float16 half8 __attribute__((ext_vector_type(8)));
typedef _Float16 half4 __attribute__((ext_vector_type(4)));
typedef float    f32x4 __attribute__((ext_vector_type(4)));

// 16B-chunk XOR swizzle (rows of 64 halves = 8 chunks of 8).
__device__ __forceinline__ int swz(int row, int chunk) {
  return (row << 3) + (chunk ^ (row & 7));
}

__global__ __launch_bounds__(256, 4)
void rbf_causal_attn(const float* __restrict__ Qp, const float* __restrict__ Kp,
                     const float* __restrict__ Vp, float* __restrict__ Op) {
  __shared__ half8 sKh[BN * 8];      //  8 KB
  __shared__ half8 sKl[BN * 8];      //  8 KB
  __shared__ half8 sVt[HD * 8];      //  8 KB  v^T: row=d, col=j
  __shared__ half8 sP[4 * 16 * 8];   //  8 KB  per-wave P round-trip
  __shared__ float sKsq[BN];         // s*log2e*|k|^2 - 14  (bias folded)

  const int x    = blockIdx.x;
  const int bh   = (x & 7) * 4 + ((x >> 3) & 3);  // 4 bh per XCD for K/V L2 reuse
  const int p    = (x >> 5) & 15;    // pair index 0..15
  const int a    = (x >> 9) & 1;     // arc 0/1
  const int qtA  = 31 - p;           // 16..31
  const int nA   = qtA + 1;          // 17..32 j-tiles for tile A
  const int qtB  = p;                // 0..15, nB = p+1
  const int g0   = a ? 17 : 0;
  const int g1   = a ? 33 : 17;

  const int t    = threadIdx.x;
  const int w    = t >> 6;
  const int lane = t & 63;
  const int ln   = lane & 15;
  const int q4   = lane >> 4;

  const float* Kg = Kp + (size_t)bh * S_LEN * HD;
  const float* Vg = Vp + (size_t)bh * S_LEN * HD;

  f32x4 kreg[4];      // K prefetch registers (one tile)
  float vreg[16];     // V prefetch registers (one tile, column d=lane)
  half8 qh[2], ql[2]; // Q fragments (rows w*16+ln)
  float qsqv[4];      // s*log2e*|q_row|^2 for rows q4*4+r
  f32x4 oacc[4] = {}; // scaled by 2^14

  // ---- load this wave's Q fragments straight from global; row |q|^2 ----
  auto load_q = [&](int qt) {
    const float* Qg = Qp + ((size_t)bh * S_LEN + (size_t)qt * BM) * HD;
    float ss = 0.f;
    #pragma unroll
    for (int kc = 0; kc < 2; ++kc) {
      const float* base = Qg + (w * 16 + ln) * HD + kc * 32 + q4 * 8;
      const f32x4 fa = *(const f32x4*)base;
      const f32x4 fb = *(const f32x4*)(base + 4);
      half8 h, l;
      #pragma unroll
      for (int c = 0; c < 4; ++c) {
        const float va = fa[c], vb = fb[c];
        const _Float16 ha = (_Float16)va, hb = (_Float16)vb;
        h[c]     = ha;  h[c + 4] = hb;
        l[c]     = (_Float16)(va - (float)ha);
        l[c + 4] = (_Float16)(vb - (float)hb);
        ss += va * va + vb * vb;
      }
      qh[kc] = h;  ql[kc] = l;
    }
    ss += __shfl_xor(ss, 16);      // reduce over q4 groups -> row sum at lane ln
    ss += __shfl_xor(ss, 32);
    ss *= (SCALE * LOG2E);
    #pragma unroll
    for (int r = 0; r < 4; ++r) qsqv[r] = __shfl(ss, q4 * 4 + r);
  };

  // ---- issue global loads for j-tile jt into registers (no wait) ----
  auto prefetch = [&](int jt) {
    const float* Kt = Kg + (size_t)jt * BN * HD;
    #pragma unroll
    for (int i = 0; i < 4; ++i) {
      const int id = t + 256 * i;
      kreg[i] = *(const f32x4*)(Kt + (id >> 4) * HD + (id & 15) * 4);
    }
    const float* Vt = Vg + (size_t)jt * BN * HD;
    #pragma unroll
    for (int i = 0; i < 16; ++i)
      vreg[i] = Vt[(w * 16 + i) * HD + lane];   // 256B-coalesced per instr
  };

  // ---- convert prefetched K/V registers into LDS ----
  auto stage_kv = [&]() {
    #pragma unroll
    for (int i = 0; i < 4; ++i) {
      const int id  = t + 256 * i;
      const int row = id >> 4;
      const int d4  = id & 15;
      const f32x4 f = kreg[i];
      half4 hv, lv;
      float ss = 0.f;
      #pragma unroll
      for (int c = 0; c < 4; ++c) {
        const float fv = f[c];
        const _Float16 hi = (_Float16)fv;
        hv[c] = hi;
        lv[c] = (_Float16)(fv - (float)hi);
        ss += fv * fv;
      }
      ((half4*)&sKh[swz(row, d4 >> 1)])[d4 & 1] = hv;
      ((half4*)&sKl[swz(row, d4 >> 1)])[d4 & 1] = lv;
      #pragma unroll
      for (int m = 1; m < 16; m <<= 1) ss += __shfl_xor(ss, m);
      if ((t & 15) == 0) sKsq[row] = ss * (SCALE * LOG2E) - 14.0f;
    }
    // V: thread holds column d=lane, rows j = w*16..w*16+15 -> transposed store
    half8 v0, v1;
    #pragma unroll
    for (int i = 0; i < 8; ++i) { v0[i] = (_Float16)vreg[i]; v1[i] = (_Float16)vreg[8 + i]; }
    sVt[swz(lane, 2 * w + 0)] = v0;
    sVt[swz(lane, 2 * w + 1)] = v1;
  };

  // ---- one j-tile: QK (hi/lo), prefetch njt, exp2, P round-trip, PV ----
  auto compute = [&](int qt, int jt, int njt) {
    f32x4 acc[4] = {};
    #pragma unroll
    for (int kc = 0; kc < 2; ++kc)
      #pragma unroll
      for (int nt = 0; nt < 4; ++nt) {
        const int row = nt * 16 + ln;
        const int ch  = ((kc << 2) + q4) ^ (ln & 7);
        const half8 kh = sKh[(row << 3) + ch];
        const half8 kl = sKl[(row << 3) + ch];
        acc[nt] = __builtin_amdgcn_mfma_f32_16x16x32_f16(qh[kc], kh, acc[nt], 0, 0, 0);
        acc[nt] = __builtin_amdgcn_mfma_f32_16x16x32_f16(qh[kc], kl, acc[nt], 0, 0, 0);
        acc[nt] = __builtin_amdgcn_mfma_f32_16x16x32_f16(ql[kc], kh, acc[nt], 0, 0, 0);
      }

    if (njt >= 0) prefetch(njt);   // kreg/vreg dead during QK; refill here

    const bool need_mask = (jt == qt);   // BM==BN: only diagonal tile partial
    const int mrow = w * 16 + q4 * 4;    // within-64-row-tile row base
    #pragma unroll
    for (int nt = 0; nt < 4; ++nt) {
      const float ks = sKsq[nt * 16 + ln];
      #pragma unroll
      for (int r = 0; r < 4; ++r) {
        // log2(2^14 p) = 2s*log2e*qk - s*log2e*q^2 - (s*log2e*k^2 - 14)
        const float lg = __builtin_fmaf((2.f * SCALE * LOG2E), acc[nt][r], -qsqv[r]) - ks;
        float pv = __builtin_amdgcn_exp2f(lg);
        if (need_mask && (nt * 16 + ln > mrow + r)) pv = 0.f;
        const int prow = q4 * 4 + r;       // C-layout: row = quad*4+reg
        const int col  = nt * 16 + ln;     //           col = lane&15
        ((_Float16*)&sP[(w << 7) + swz(prow, col >> 3)])[col & 7] = (_Float16)pv;
      }
    }
    half8 pa[2];
    #pragma unroll
    for (int kc = 0; kc < 2; ++kc)
      pa[kc] = sP[(w << 7) + swz(ln, (kc << 2) + q4)];

    #pragma unroll
    for (int dt = 0; dt < 4; ++dt) {
      const int row = dt * 16 + ln;
      const half8 vf0 = sVt[(row << 3) + ((0 + q4) ^ (ln & 7))];
      const half8 vf1 = sVt[(row << 3) + ((4 + q4) ^ (ln & 7))];
      oacc[dt] = __builtin_amdgcn_mfma_f32_16x16x32_f16(pa[0], vf0, oacc[dt], 0, 0, 0);
      oacc[dt] = __builtin_amdgcn_mfma_f32_16x16x32_f16(pa[1], vf1, oacc[dt], 0, 0, 0);
    }
  };

  // ---- flush accumulator (x 2^-14), atomic (tiles have multiple owners) ----
  auto flush = [&](int qt) {
    #pragma unroll
    for (int dt = 0; dt < 4; ++dt)
      #pragma unroll
      for (int r = 0; r < 4; ++r) {
        const int row = qt * BM + w * 16 + q4 * 4 + r;
        atomicAdd(Op + ((size_t)bh * S_LEN + row) * HD + dt * 16 + ln,
                  oacc[dt][r] * 6.103515625e-05f);
      }
  };

  // ---- main: arc [g0, g1) of the pair's 33 j-tile iterations ----
  int qt, jt;
  if (g0 < nA) { qt = qtA; jt = g0; }
  else         { qt = qtB; jt = g0 - nA; }
  load_q(qt);
  prefetch(jt);
  __syncthreads();

  const int niter = g1 - g0;
  #pragma unroll 1
  for (int step = 0; step < niter; ++step) {
    if (qt == qtA && jt == nA) {       // cross from tile A into tile B
      flush(qtA);
      #pragma unroll
      for (int dt = 0; dt < 4; ++dt) oacc[dt] = f32x4{0.f, 0.f, 0.f, 0.f};
      load_q(qtB);
      qt = qtB; jt = 0;
    }
    stage_kv();
    __syncthreads();
    int njt = -1;
    if (step + 1 < niter) {
      njt = jt + 1;
      if (qt == qtA && njt == nA) njt = 0;
    }
    compute(qt, jt, njt);
    __syncthreads();
    ++jt;
  }
  flush(qt);
}

extern "C" void kernel_launch(void* const* d_in, const int* in_sizes, int n_in,
                              void* d_out, int out_size, void* d_ws, size_t ws_size,
                              hipStream_t stream) {
  const float* q = (const float*)d_in[0];
  const float* k = (const float*)d_in[1];
  const float* v = (const float*)d_in[2];
  float* o = (float*)d_out;
  hipMemsetAsync(d_out, 0, (size_t)out_size * sizeof(float), stream);
  rbf_causal_attn<<<dim3(1024), dim3(256), 0, stream>>>(q, k, v, o);
}

// Round 6
// 153.971 us; speedup vs baseline: 2.2900x; 1.6316x over previous
//
#include <hip/hip_runtime.h>

// RBF causal attention: out[m] = sum_{j<=m} exp(-0.125*||q_m - k_j||^2) * v_j
// B=2 H=16 S=2048 D=64, fp32 in/out.
// fp16 hi/lo-split QK (3 MFMAs ~ fp32 accuracy), fp16 PV with p scaled 2^14.
// R6: (a) pass-1 kernel preconverts K->f16 hi/lo, V->V^T f16, ksq into d_ws
// in pre-swizzled LDS-image order (once, not 16x per reuse); (b) main kernel
// stages tiles via global_load_lds width=16 (no VGPR round trip, no per-iter
// convert VALU -> register demand ~150 fits 3 waves/SIMD cap 170 w/o spill);
// (c) 32x32x16 MFMA with S^T=K*Q^T so P C-layout writes out as contiguous
// half4 (b64) and reads back as b128 A-frags: halves LDS frag traffic/FLOP.

constexpr int S_LEN = 2048;
constexpr int HD    = 64;
constexpr int BM    = 128;   // Q rows per block (4 waves x 32 rows)
constexpr int BN    = 64;    // K/V rows per tile
constexpr float SCALE = 0.125f;
constexpr float LOG2E = 1.44269504088896f;
constexpr float C2    = 2.f * SCALE * LOG2E;   // coeff on qk term
constexpr int TS = 25600;    // ws bytes per (bh,jt) tile: Khi 8K|Klo 8K|Vt 8K|ksq 256|pad

typedef _Float16 half8  __attribute__((ext_vector_type(8)));
typedef _Float16 half4  __attribute__((ext_vector_type(4)));
typedef float    f32x4  __attribute__((ext_vector_type(4)));
typedef float    f32x16 __attribute__((ext_vector_type(16)));

// 16B-chunk XOR swizzle (rows of 64 halves = 8 chunks of 8 halves).
__device__ __forceinline__ int swz(int row, int chunk) {
  return (row << 3) + (chunk ^ (row & 7));
}

// ---------------- pass 1: preconvert K/V into LDS-image tiles in ws ----------
__global__ __launch_bounds__(256, 4)
void preconvert(const float* __restrict__ Kp, const float* __restrict__ Vp,
                char* __restrict__ ws) {
  const int x  = blockIdx.x;
  const int bh = x >> 5, jt = x & 31;
  const int t  = threadIdx.x;
  const int w  = t >> 6, lane = t & 63;

  char* img = ws + (size_t)(bh * 32 + jt) * TS;
  half8* imgKh = (half8*)img;
  half8* imgKl = imgKh + 512;
  half8* imgVt = imgKh + 1024;
  float* ksqp  = (float*)(img + 24576);

  const float* Kt = Kp + ((size_t)bh * S_LEN + jt * BN) * HD;
  const float* Vt = Vp + ((size_t)bh * S_LEN + jt * BN) * HD;

  #pragma unroll
  for (int i = 0; i < 4; ++i) {
    const int id  = t + 256 * i;
    const int row = id >> 4;
    const int d4  = id & 15;
    const f32x4 f = *(const f32x4*)(Kt + row * HD + d4 * 4);
    half4 hv, lv;
    float ss = 0.f;
    #pragma unroll
    for (int c = 0; c < 4; ++c) {
      const float fv = f[c];
      const _Float16 hi = (_Float16)fv;
      hv[c] = hi;
      lv[c] = (_Float16)(fv - (float)hi);
      ss += fv * fv;
    }
    ((half4*)&imgKh[swz(row, d4 >> 1)])[d4 & 1] = hv;
    ((half4*)&imgKl[swz(row, d4 >> 1)])[d4 & 1] = lv;
    #pragma unroll
    for (int m = 1; m < 16; m <<= 1) ss += __shfl_xor(ss, m);
    if ((t & 15) == 0) ksqp[row] = ss * (SCALE * LOG2E) - 14.0f;  // bias folded
  }
  // V transpose: lane holds col d=lane, rows w*16..w*16+15
  float vr[16];
  #pragma unroll
  for (int i = 0; i < 16; ++i) vr[i] = Vt[(w * 16 + i) * HD + lane];
  half8 v0, v1;
  #pragma unroll
  for (int i = 0; i < 8; ++i) { v0[i] = (_Float16)vr[i]; v1[i] = (_Float16)vr[8 + i]; }
  imgVt[swz(lane, 2 * w + 0)] = v0;
  imgVt[swz(lane, 2 * w + 1)] = v1;
}

// ---------------- main kernel ------------------------------------------------
__global__ __launch_bounds__(256, 3)
void rbf_causal_attn(const float* __restrict__ Qp, const char* __restrict__ ws,
                     float* __restrict__ Op) {
  __shared__ __align__(16) char sTile[TS];     // Khi|Klo|Vt|ksq image
  __shared__ half8 sP[4 * 32 * 8];             // per-wave P round-trip (16 KB)

  half8* sKh = (half8*)sTile;
  half8* sKl = sKh + 512;
  half8* sVt = sKh + 1024;
  const float* sksq = (const float*)(sTile + 24576);

  const int x    = blockIdx.x;                 // 0..767
  const int xcd  = x & 7;
  const int idx  = x >> 3;                     // 0..95
  const int bh   = xcd * 4 + (idx & 3);        // 4 bh per XCD (L2 reuse of ws)
  const int a    = idx >> 2;                   // arc 0..23
  const int t    = threadIdx.x;
  const int w    = t >> 6;
  const int lane = t & 63;
  const int l31  = lane & 31;
  const int l5   = lane >> 5;                  // 0/1

  // arc: first 8 arcs take 12 j-iters, rest 11 (total 272 per bh)
  const int start = (a < 8) ? 12 * a : 96 + 11 * (a - 8);
  const int len   = (a < 8) ? 12 : 11;

  // flattened (qt descending, jt ascending) -> (qt, jt)
  int rem = start, qt = 15;
  while (rem >= 2 * qt + 2) { rem -= 2 * qt + 2; --qt; }
  int jt = rem;

  const char* wsb = ws + (size_t)bh * 32 * TS;

  half8 qh[4], ql[4];   // B-operand Q frags: lane holds row w*32+l31, k-chunk ks*16+l5*8
  float qsq;            // SCALE*LOG2E*|q_row|^2
  f32x16 oacc[2];       // O accumulator (x 2^14), dtile 0/1
  #pragma unroll
  for (int d = 0; d < 2; ++d)
    #pragma unroll
    for (int e = 0; e < 16; ++e) oacc[d][e] = 0.f;

  auto load_q = [&](int qtile) {
    const float* Qg = Qp + ((size_t)bh * S_LEN + (size_t)qtile * BM + w * 32 + l31) * HD;
    float ss = 0.f;
    #pragma unroll
    for (int ks = 0; ks < 4; ++ks) {
      const int d0 = ks * 16 + l5 * 8;
      const f32x4 fa = *(const f32x4*)(Qg + d0);
      const f32x4 fb = *(const f32x4*)(Qg + d0 + 4);
      half8 h, l;
      #pragma unroll
      for (int c = 0; c < 4; ++c) {
        const float va = fa[c], vb = fb[c];
        const _Float16 ha = (_Float16)va, hb = (_Float16)vb;
        h[c] = ha;  h[c + 4] = hb;
        l[c] = (_Float16)(va - (float)ha);
        l[c + 4] = (_Float16)(vb - (float)hb);
        ss += va * va + vb * vb;
      }
      qh[ks] = h;  ql[ks] = l;
    }
    ss += __shfl_xor(ss, 32);   // combine l5 halves -> full row sum
    qsq = ss * (SCALE * LOG2E);
  };

  auto flush = [&](int qtile) {
    #pragma unroll
    for (int dt = 0; dt < 2; ++dt)
      #pragma unroll
      for (int r = 0; r < 16; ++r) {
        const int row = qtile * BM + w * 32 + (r & 3) + 8 * (r >> 2) + 4 * l5;
        atomicAdd(Op + ((size_t)bh * S_LEN + row) * HD + dt * 32 + l31,
                  oacc[dt][r] * 6.103515625e-05f);   // * 2^-14
      }
  };

  load_q(qt);

  #pragma unroll 1
  for (int step = 0; step < len; ++step) {
    if (jt > 2 * qt + 1) {               // cross into next (smaller) q-tile
      flush(qt);
      #pragma unroll
      for (int d = 0; d < 2; ++d)
        #pragma unroll
        for (int e = 0; e < 16; ++e) oacc[d][e] = 0.f;
      --qt; jt = 0;
      load_q(qt);
    }

    // ---- stage tile image into LDS via direct global->LDS DMA ----
    const char* gt = wsb + (size_t)jt * TS;
    #pragma unroll
    for (int i = 0; i < 6; ++i) {
      const int off = w * 6144 + i * 1024;
      __builtin_amdgcn_global_load_lds((const unsigned int*)(gt + off + lane * 16),
                                       (unsigned int*)(sTile + off), 16, 0, 0);
    }
    if (w == 0)
      __builtin_amdgcn_global_load_lds((const unsigned int*)(gt + 24576 + lane * 16),
                                       (unsigned int*)(sTile + 24576), 16, 0, 0);
    __syncthreads();   // drains vmcnt -> image ready

    // ---- S^T = K * Q^T (hi/lo), exp2, P->LDS, then O += P*V ----
    half8* sPw = sP + w * 256;           // this wave's 32x64-half P buffer
    const bool need_mask = (jt >= 2 * qt);
    const int mg = qt * BM + w * 32 + l31;

    #pragma unroll
    for (int ntile = 0; ntile < 2; ++ntile) {
      f32x16 acc;
      #pragma unroll
      for (int e = 0; e < 16; ++e) acc[e] = 0.f;
      #pragma unroll
      for (int ks = 0; ks < 4; ++ks) {
        const int rr = ntile * 32 + l31;
        const int ch = (2 * ks + l5) ^ (rr & 7);
        const half8 kh = sKh[(rr << 3) + ch];
        const half8 kl = sKl[(rr << 3) + ch];
        acc = __builtin_amdgcn_mfma_f32_32x32x16_f16(kh, qh[ks], acc, 0, 0, 0);
        acc = __builtin_amdgcn_mfma_f32_32x32x16_f16(kh, ql[ks], acc, 0, 0, 0);
        acc = __builtin_amdgcn_mfma_f32_32x32x16_f16(kl, qh[ks], acc, 0, 0, 0);
      }
      // exp + store P[m=l31][n] as contiguous half4 runs
      #pragma unroll
      for (int g = 0; g < 4; ++g) {
        // ksq for n_local = 8g + 4*l5 + (0..3)  (f32x4, broadcast-friendly)
        const f32x4 k4 = *(const f32x4*)(sksq + ntile * 32 + 8 * g + 4 * l5);
        half4 h4;
        #pragma unroll
        for (int rr = 0; rr < 4; ++rr) {
          const int reg = g * 4 + rr;
          // log2(2^14 p) = C2*qk - qsq' - (ksq' - 14)
          const float lg = __builtin_fmaf(C2, acc[reg], -k4[rr]) - qsq;
          float pv = __builtin_amdgcn_exp2f(lg);
          if (need_mask) {
            const int ng = jt * BN + ntile * 32 + 8 * g + 4 * l5 + rr;
            if (ng > mg) pv = 0.f;
          }
          h4[rr] = (_Float16)pv;
        }
        ((half4*)&sPw[swz(l31, ntile * 4 + g)])[l5] = h4;
      }
    }

    // PV: O[m][d] += P[m][n] V[n][d];  A = P frags, B = V^T frags
    #pragma unroll
    for (int ks = 0; ks < 4; ++ks) {
      const half8 pa = sPw[(l31 << 3) + ((2 * ks + l5) ^ (l31 & 7))];
      #pragma unroll
      for (int dt = 0; dt < 2; ++dt) {
        const int rr = dt * 32 + l31;
        const half8 vt = sVt[(rr << 3) + ((2 * ks + l5) ^ (rr & 7))];
        oacc[dt] = __builtin_amdgcn_mfma_f32_32x32x16_f16(pa, vt, oacc[dt], 0, 0, 0);
      }
    }
    __syncthreads();   // protect sTile before next iteration's DMA
    ++jt;
  }
  flush(qt);
}

extern "C" void kernel_launch(void* const* d_in, const int* in_sizes, int n_in,
                              void* d_out, int out_size, void* d_ws, size_t ws_size,
                              hipStream_t stream) {
  const float* q = (const float*)d_in[0];
  const float* k = (const float*)d_in[1];
  const float* v = (const float*)d_in[2];
  float* o = (float*)d_out;
  hipMemsetAsync(d_out, 0, (size_t)out_size * sizeof(float), stream);
  preconvert<<<dim3(1024), dim3(256), 0, stream>>>(k, v, (char*)d_ws);
  rbf_causal_attn<<<dim3(768), dim3(256), 0, stream>>>(q, (const char*)d_ws, o);
}